// Round 9
// baseline (2267.687 us; speedup 1.0000x reference)
//
#include <hip/hip_runtime.h>
#include <stdint.h>

#define NPTS  2048
#define BATCH 2
#define KNN   128
#define C1    128
#define C2    256
#define C3    512
#define C4    128
#define NGROUP (BATCH * NPTS)    // 4096
#define FEAT_ELEMS (BATCH * C4 * NPTS)  // 524288
#define HBINS 2048
#define NREP  8

typedef short short8 __attribute__((ext_vector_type(8)));
typedef short short4v __attribute__((ext_vector_type(4)));
typedef float float4v __attribute__((ext_vector_type(4)));
#define MFMA16(a, b, c) __builtin_amdgcn_mfma_f32_16x16x32_bf16(a, b, c, 0, 0, 0)

__device__ __host__ inline unsigned short f2bf(float x) {
    unsigned u = __float_as_uint(x);
    return (unsigned short)((u + 0x7fffu + ((u >> 16) & 1u)) >> 16);
}
__device__ inline float bf2f(unsigned short s) {
    return __uint_as_float(((unsigned)s) << 16);
}

// ---------------------------------------------------------------------------
__global__ void prep_kernel(const float* __restrict__ w2, const float* __restrict__ w3,
                            const float* __restrict__ w4,
                            float* __restrict__ w3t,
                            unsigned short* __restrict__ w2hg, unsigned short* __restrict__ w2lg,
                            unsigned short* __restrict__ w3bh, unsigned short* __restrict__ w3bl,
                            unsigned short* __restrict__ w4hg, unsigned short* __restrict__ w4lg) {
    int tid = blockIdx.x * blockDim.x + threadIdx.x;
    int stride = gridDim.x * blockDim.x;
    for (int i = tid; i < C2 * C1; i += stride) {
        float v = w2[i];
        unsigned short h = f2bf(v);
        w2hg[i] = h; w2lg[i] = f2bf(v - bf2f(h));
    }
    for (int i = tid; i < C3 * C3; i += stride) w3t[(i & (C3 - 1)) * C3 + (i >> 9)] = w3[i];
    for (int i = tid; i < C3 * C2; i += stride) {
        int m = i >> 8, k = i & 255;
        float v = w3[m * C3 + C2 + k];
        unsigned short h = f2bf(v);
        w3bh[i] = h; w3bl[i] = f2bf(v - bf2f(h));
    }
    for (int i = tid; i < C4 * C3; i += stride) {
        float v = w4[i];
        unsigned short h = f2bf(v);
        w4hg[i] = h; w4lg[i] = f2bf(v - bf2f(h));
    }
}

// ---------------------------------------------------------------------------
// K0: exact kNN via 2-level radix select (bit-identical distance math) + BN1.
__launch_bounds__(256)
__global__ void knn_kernel(const float* __restrict__ pos,
                           const float* __restrict__ w1, const float* __restrict__ b1,
                           float* __restrict__ out,
                           float* __restrict__ gp,
                           float* __restrict__ bn1sumr, float* __restrict__ bn1sqr) {
    __shared__ float px[NPTS], py[NPTS], pz[NPTS];
    __shared__ unsigned int dbits[NPTS];
    __shared__ unsigned int hist[HBINS];
    __shared__ unsigned int seg[256];
    __shared__ unsigned long long cand[256];
    __shared__ float gsx[KNN], gsy[KNN], gsz[KNN];
    __shared__ float red[256];
    __shared__ unsigned int s_b1, s_c0, s_p22, s_cnt;

    int t = threadIdx.x;
    int blk = blockIdx.x;
    int b = blk >> 11, n = blk & (NPTS - 1);
    const float* pb = pos + (size_t)b * NPTS * 3;
    for (int i = t; i < NPTS; i += 256) {
        px[i] = pb[i * 3 + 0]; py[i] = pb[i * 3 + 1]; pz[i] = pb[i * 3 + 2];
    }
    for (int i = t; i < HBINS; i += 256) hist[i] = 0;
    if (t == 0) s_cnt = 0;
    __syncthreads();

    float qx = px[n], qy = py[n], qz = pz[n];
    {
        #pragma clang fp contract(off)
        float sqi = (qx * qx + qy * qy) + qz * qz;
        for (int j = t; j < NPTS; j += 256) {
            float xj = px[j], yj = py[j], zj = pz[j];
            float sqj = (xj * xj + yj * yj) + zj * zj;
            float dot = fmaf(qz, zj, fmaf(qy, yj, qx * xj));
            float d2 = (sqi + sqj) - 2.0f * dot;
            float dist = sqrtf(fmaxf(d2, 0.0f));
            unsigned int bits = __float_as_uint(dist);
            dbits[j] = bits;
            atomicAdd(&hist[bits >> 20], 1u);
        }
    }
    __syncthreads();
    {
        unsigned int s = 0;
        #pragma unroll
        for (int q = 0; q < 8; ++q) s += hist[t * 8 + q];
        seg[t] = s;
        __syncthreads();
        for (int off = 1; off < 256; off <<= 1) {
            unsigned int v = seg[t];
            unsigned int u = (t >= off) ? seg[t - off] : 0;
            __syncthreads();
            seg[t] = v + u;
            __syncthreads();
        }
        unsigned int before = (t == 0) ? 0u : seg[t - 1];
        unsigned int incl = seg[t];
        if (before <= 127u && 127u < incl) {
            unsigned int c = before;
            for (int q = 0; q < 8; ++q) {
                unsigned int h = hist[t * 8 + q];
                if (c + h > 127u) { s_b1 = t * 8 + q; s_c0 = c; break; }
                c += h;
            }
        }
    }
    __syncthreads();
    unsigned int B1 = s_b1, c0 = s_c0;
    for (int i = t; i < HBINS; i += 256) hist[i] = 0;
    __syncthreads();
    for (int j = t; j < NPTS; j += 256) {
        unsigned int bits = dbits[j];
        if ((bits >> 20) == B1) atomicAdd(&hist[(bits >> 9) & 0x7FFu], 1u);
    }
    __syncthreads();
    {
        unsigned int target = 127u - c0;
        unsigned int s = 0;
        #pragma unroll
        for (int q = 0; q < 8; ++q) s += hist[t * 8 + q];
        seg[t] = s;
        __syncthreads();
        for (int off = 1; off < 256; off <<= 1) {
            unsigned int v = seg[t];
            unsigned int u = (t >= off) ? seg[t - off] : 0;
            __syncthreads();
            seg[t] = v + u;
            __syncthreads();
        }
        unsigned int before = (t == 0) ? 0u : seg[t - 1];
        unsigned int incl = seg[t];
        if (before <= target && target < incl) {
            unsigned int c = before;
            for (int q = 0; q < 8; ++q) {
                unsigned int h = hist[t * 8 + q];
                if (c + h > target) { s_p22 = (B1 << 11) | (unsigned)(t * 8 + q); break; }
                c += h;
            }
        }
    }
    cand[t] = 0xFFFFFFFFFFFFFFFFull;
    __syncthreads();
    unsigned int P22 = s_p22;
    for (int j = t; j < NPTS; j += 256) {
        unsigned int bits = dbits[j];
        if ((bits >> 9) <= P22) {
            unsigned int pos_ = atomicAdd(&s_cnt, 1u);
            if (pos_ < 256u) cand[pos_] = ((unsigned long long)bits << 32) | (unsigned int)j;
        }
    }
    __syncthreads();
    for (int k2 = 2; k2 <= 256; k2 <<= 1) {
        for (int s2 = k2 >> 1; s2 > 0; s2 >>= 1) {
            int l = t ^ s2;
            if (l > t) {
                unsigned long long a = cand[t], c = cand[l];
                bool up = ((t & k2) == 0);
                if ((a > c) == up) { cand[t] = c; cand[l] = a; }
            }
            __syncthreads();
        }
    }
    if (t < KNN) {
        unsigned int j = (unsigned int)(cand[t] & 0xffffffffu);
        out[FEAT_ELEMS + (size_t)blk * KNN + t] = (float)j;
        float gx_ = px[j] - qx, gy_ = py[j] - qy, gz_ = pz[j] - qz;
        gsx[t] = gx_; gsy[t] = gy_; gsz[t] = gz_;
        float* g = gp + ((size_t)blk * KNN + t) * 3;
        g[0] = gx_; g[1] = gy_; g[2] = gz_;
    }
    __syncthreads();
    int c = t & (C1 - 1);
    int half = t >> 7;
    float wa = w1[c * 3 + 0], wb = w1[c * 3 + 1], wc = w1[c * 3 + 2], bc = b1[c];
    float s = 0.f, q = 0.f;
    for (int r = half * 64; r < half * 64 + 64; ++r) {
        float f = wa * gsx[r] + wb * gsy[r] + wc * gsz[r] + bc;
        s += f; q += f * f;
    }
    red[t] = s; __syncthreads();
    int rep = blk & (NREP - 1);
    if (t < C1) atomicAdd(bn1sumr + rep * C1 + t, red[t] + red[t + C1]);
    __syncthreads();
    red[t] = q; __syncthreads();
    if (t < C1) atomicAdd(bn1sqr + rep * C1 + t, red[t] + red[t + C1]);
}

// ---------------------------------------------------------------------------
__global__ void bn_finalize(const float* __restrict__ sumr, const float* __restrict__ sqr,
                            const float* __restrict__ g, const float* __restrict__ be,
                            float* __restrict__ scale, float* __restrict__ shift,
                            int nch, float inv_count) {
    int c = blockIdx.x * blockDim.x + threadIdx.x;
    if (c < nch) {
        float s = 0.f, q = 0.f;
        for (int r = 0; r < NREP; ++r) { s += sumr[r * nch + c]; q += sqr[r * nch + c]; }
        float m = s * inv_count;
        float v = fmaxf(q * inv_count - m * m, 0.f);
        float sc = g[c] / sqrtf(v + 1e-5f);
        scale[c] = sc;
        shift[c] = be[c] - m * sc;
    }
}

#define H1S 136   // h1/g3 row stride (shorts)
#define F2S 264   // f2 row stride (shorts)
#define NC  64    // neighbors per chunk

// ---------------------------------------------------------------------------
// stats2 (16x16 MFMA, 256 thr, 2 chunks of 64 neighbors, LDS < 80 KiB so
// 2 blocks/CU co-reside in different phases). launch_bounds (256,1): the
// (256,2) variant forced a 128-VGPR split and spilled ~100 KB/block to
// scratch (r8: FETCH 409 MB, WRITE 381 MB).
__launch_bounds__(256, 1)
__global__ void stats2_mfma_kernel(const float* __restrict__ gp,
                                   const float* __restrict__ w1, const float* __restrict__ b1,
                                   const float* __restrict__ sc1, const float* __restrict__ sh1,
                                   const unsigned short* __restrict__ w2hg, const unsigned short* __restrict__ w2lg,
                                   const float* __restrict__ b2,
                                   const float* __restrict__ w3t,
                                   const unsigned short* __restrict__ w3bh, const unsigned short* __restrict__ w3bl,
                                   const float* __restrict__ b3,
                                   float* __restrict__ c3buf,
                                   float* __restrict__ bn2sumr, float* __restrict__ bn2sqr) {
    __shared__ __align__(16) unsigned short ovl[2 * NC * H1S];   // h1 hi/lo
    __shared__ __align__(16) unsigned short f2s[NC * F2S];       // f2 single bf16 [n][c2]
    __shared__ float w1s[C1 * 3], b1s[C1], sc1s[C1], sh1s[C1], b2s[C2];
    __shared__ float fgs[C2];
    __shared__ float c3s[C3];
    __shared__ float sSacc[C3], qSacc[C3];

    unsigned short* aH = ovl;
    unsigned short* aL = ovl + NC * H1S;

    int t = threadIdx.x, blk = blockIdx.x;
    int lane = t & 63, wave = t >> 6;
    int lrow = lane & 15, lq = lane >> 4;

    const float* g = gp + (size_t)blk * KNN * 3;
    for (int i = t; i < C1 * 3; i += 256) w1s[i] = w1[i];
    if (t < C1) { b1s[t] = b1[t]; sc1s[t] = sc1[t]; sh1s[t] = sh1[t]; }
    b2s[t] = b2[t];
    fgs[t] = -3.4e38f;
    for (int i = t; i < C3; i += 256) { sSacc[i] = 0.f; qSacc[i] = 0.f; }
    __syncthreads();

    const float4v zero4 = {0.f, 0.f, 0.f, 0.f};

    for (int chk = 0; chk < 2; ++chk) {
        // ---- conv1 + BN1 + ReLU -> h1 hi/lo for this 64-neighbor chunk ----
        {
            int n = t >> 2, cb = (t & 3) * 32;
            int jn = chk * NC + n;
            float gx = g[jn * 3], gy = g[jn * 3 + 1], gz = g[jn * 3 + 2];
            #pragma unroll
            for (int e8 = 0; e8 < 4; ++e8) {
                short8 vh, vl;
                #pragma unroll
                for (int e = 0; e < 8; ++e) {
                    int c = cb + e8 * 8 + e;
                    float f = w1s[c*3] * gx + w1s[c*3+1] * gy + w1s[c*3+2] * gz + b1s[c];
                    float v = fmaxf(f * sc1s[c] + sh1s[c], 0.f);
                    unsigned short h = f2bf(v);
                    vh[e] = (short)h;
                    vl[e] = (short)f2bf(v - bf2f(h));
                }
                *(short8*)&aH[n * H1S + cb + e8 * 8] = vh;
                *(short8*)&aL[n * H1S + cb + e8 * 8] = vl;
            }
        }
        __syncthreads();

        // ---- conv2: M=256, K=128, N=64; wave: 4mt x 4nt ----
        {
            float4v acc[4][4];
            #pragma unroll
            for (int i = 0; i < 4; ++i)
                #pragma unroll
                for (int j = 0; j < 4; ++j) acc[i][j] = zero4;
            for (int ks = 0; ks < 4; ++ks) {
                int ko = ks * 32 + lq * 8;
                short8 bh[4], bl[4];
                #pragma unroll
                for (int j = 0; j < 4; ++j) {
                    bh[j] = *(const short8*)&aH[(j * 16 + lrow) * H1S + ko];
                    bl[j] = *(const short8*)&aL[(j * 16 + lrow) * H1S + ko];
                }
                #pragma unroll
                for (int i = 0; i < 4; ++i) {
                    int m = (wave * 4 + i) * 16 + lrow;
                    short8 ah = *(const short8*)&w2hg[m * C1 + ko];
                    short8 al = *(const short8*)&w2lg[m * C1 + ko];
                    #pragma unroll
                    for (int j = 0; j < 4; ++j) {
                        acc[i][j] = MFMA16(ah, bh[j], acc[i][j]);
                        acc[i][j] = MFMA16(ah, bl[j], acc[i][j]);
                        acc[i][j] = MFMA16(al, bh[j], acc[i][j]);
                    }
                }
            }
            // epilogue: bias, pack f2 bf16, fg running max
            #pragma unroll
            for (int i = 0; i < 4; ++i) {
                int mb = (wave * 4 + i) * 16 + lq * 4;
                float bb0 = b2s[mb], bb1 = b2s[mb+1], bb2 = b2s[mb+2], bb3 = b2s[mb+3];
                float mx[4] = {-3.4e38f, -3.4e38f, -3.4e38f, -3.4e38f};
                #pragma unroll
                for (int j = 0; j < 4; ++j) {
                    int n = j * 16 + lrow;
                    float v0 = acc[i][j][0] + bb0, v1 = acc[i][j][1] + bb1;
                    float v2 = acc[i][j][2] + bb2, v3 = acc[i][j][3] + bb3;
                    short4v p;
                    p[0] = (short)f2bf(v0); p[1] = (short)f2bf(v1);
                    p[2] = (short)f2bf(v2); p[3] = (short)f2bf(v3);
                    *(short4v*)&f2s[n * F2S + mb] = p;
                    mx[0] = fmaxf(mx[0], v0); mx[1] = fmaxf(mx[1], v1);
                    mx[2] = fmaxf(mx[2], v2); mx[3] = fmaxf(mx[3], v3);
                }
                #pragma unroll
                for (int r = 0; r < 4; ++r) {
                    float v = mx[r];
                    v = fmaxf(v, __shfl_xor(v, 1));
                    v = fmaxf(v, __shfl_xor(v, 2));
                    v = fmaxf(v, __shfl_xor(v, 4));
                    v = fmaxf(v, __shfl_xor(v, 8));
                    if (lrow == 0) fgs[mb + r] = fmaxf(fgs[mb + r], v);
                }
            }
        }
        __syncthreads();

        // ---- conv3 in 4 m-slices (wave: 2mt x 4nt), accumulate BN2 moments ----
        for (int sl = 0; sl < 4; ++sl) {
            float4v acc3[2][4];
            #pragma unroll
            for (int i = 0; i < 2; ++i)
                #pragma unroll
                for (int j = 0; j < 4; ++j) acc3[i][j] = zero4;
            for (int ks = 0; ks < 8; ++ks) {
                int ko = ks * 32 + lq * 8;
                short8 bfr[4];
                #pragma unroll
                for (int j = 0; j < 4; ++j)
                    bfr[j] = *(const short8*)&f2s[(j * 16 + lrow) * F2S + ko];
                #pragma unroll
                for (int i = 0; i < 2; ++i) {
                    int mg = sl * 128 + (wave * 2 + i) * 16 + lrow;
                    short8 ah = *(const short8*)&w3bh[mg * C2 + ko];
                    short8 al = *(const short8*)&w3bl[mg * C2 + ko];
                    #pragma unroll
                    for (int j = 0; j < 4; ++j) {
                        acc3[i][j] = MFMA16(ah, bfr[j], acc3[i][j]);
                        acc3[i][j] = MFMA16(al, bfr[j], acc3[i][j]);
                    }
                }
            }
            #pragma unroll
            for (int i = 0; i < 2; ++i) {
                #pragma unroll
                for (int r = 0; r < 4; ++r) {
                    float sS = 0.f, qS = 0.f;
                    #pragma unroll
                    for (int j = 0; j < 4; ++j) {
                        float v = acc3[i][j][r];
                        sS += v; qS += v * v;
                    }
                    sS += __shfl_xor(sS, 1); qS += __shfl_xor(qS, 1);
                    sS += __shfl_xor(sS, 2); qS += __shfl_xor(qS, 2);
                    sS += __shfl_xor(sS, 4); qS += __shfl_xor(qS, 4);
                    sS += __shfl_xor(sS, 8); qS += __shfl_xor(qS, 8);
                    if (lrow == 0) {
                        int mg = sl * 128 + (wave * 2 + i) * 16 + lq * 4 + r;
                        sSacc[mg] += sS;     // unique owner (wave,i,lq,r)
                        qSacc[mg] += qS;
                    }
                }
            }
        }
        __syncthreads();   // f2s/ovl reuse + fgs/sSacc visibility for next phase
    }

    // ---- c3 = b3 + W3a·fg (fp32) ----
    {
        float c3a = b3[t], c3b = b3[t + 256];
        for (int c2_ = 0; c2_ < C2; ++c2_) {
            float f = fgs[c2_];
            c3a += w3t[(size_t)c2_ * C3 + t] * f;
            c3b += w3t[(size_t)c2_ * C3 + t + 256] * f;
        }
        c3s[t] = c3a; c3s[t + 256] = c3b;
        c3buf[(size_t)blk * C3 + t] = c3a;
        c3buf[(size_t)blk * C3 + t + 256] = c3b;
    }
    __syncthreads();
    {
        int rep = blk & (NREP - 1);
        for (int i = t; i < C3; i += 256) {
            float cc = c3s[i], sS = sSacc[i], qS = qSacc[i];
            atomicAdd(bn2sumr + rep * C3 + i, sS + 128.f * cc);
            atomicAdd(bn2sqr  + rep * C3 + i, qS + 2.f * cc * sS + 128.f * cc * cc);
        }
    }
}

// ---------------------------------------------------------------------------
// final (16x16 MFMA, 256 thr, 2 chunks of 64 neighbors, LDS < 80 KiB).
__launch_bounds__(256, 1)
__global__ void final_mfma_kernel(const float* __restrict__ gp,
                                  const float* __restrict__ w1, const float* __restrict__ b1,
                                  const float* __restrict__ sc1, const float* __restrict__ sh1,
                                  const unsigned short* __restrict__ w2hg, const unsigned short* __restrict__ w2lg,
                                  const float* __restrict__ b2,
                                  const unsigned short* __restrict__ w3bh, const unsigned short* __restrict__ w3bl,
                                  const float* __restrict__ sc2, const float* __restrict__ sh2,
                                  const unsigned short* __restrict__ w4hg, const unsigned short* __restrict__ w4lg,
                                  const float* __restrict__ b4,
                                  const float* __restrict__ c3buf, float* __restrict__ out) {
    __shared__ __align__(16) unsigned short ovl[2 * NC * H1S];   // h1 hi/lo <-> g3-slice hi/lo
    __shared__ __align__(16) unsigned short f2s[NC * F2S];
    __shared__ float w1s[C1 * 3], b1s[C1], sc1s[C1], sh1s[C1], b2s[C2];
    __shared__ float c3s[C3], sc2s[C3], sh2s[C3];
    __shared__ float fmp[C4];

    unsigned short* aH = ovl;
    unsigned short* aL = ovl + NC * H1S;

    int t = threadIdx.x, blk = blockIdx.x;
    int lane = t & 63, wave = t >> 6;
    int lrow = lane & 15, lq = lane >> 4;

    const float* g = gp + (size_t)blk * KNN * 3;
    for (int i = t; i < C1 * 3; i += 256) w1s[i] = w1[i];
    if (t < C1) { b1s[t] = b1[t]; sc1s[t] = sc1[t]; sh1s[t] = sh1[t]; }
    b2s[t] = b2[t];
    for (int i = t; i < C3; i += 256) {
        c3s[i] = c3buf[(size_t)blk * C3 + i];
        sc2s[i] = sc2[i]; sh2s[i] = sh2[i];
    }
    __syncthreads();

    const float4v zero4 = {0.f, 0.f, 0.f, 0.f};
    float rm[2][4];
    #pragma unroll
    for (int i = 0; i < 2; ++i)
        #pragma unroll
        for (int r = 0; r < 4; ++r) rm[i][r] = -3.4e38f;

    for (int chk = 0; chk < 2; ++chk) {
        __syncthreads();   // prior chunk's conv4 done reading ovl
        // ---- conv1 -> h1 hi/lo ----
        {
            int n = t >> 2, cb = (t & 3) * 32;
            int jn = chk * NC + n;
            float gx = g[jn * 3], gy = g[jn * 3 + 1], gz = g[jn * 3 + 2];
            #pragma unroll
            for (int e8 = 0; e8 < 4; ++e8) {
                short8 vh, vl;
                #pragma unroll
                for (int e = 0; e < 8; ++e) {
                    int c = cb + e8 * 8 + e;
                    float f = w1s[c*3] * gx + w1s[c*3+1] * gy + w1s[c*3+2] * gz + b1s[c];
                    float v = fmaxf(f * sc1s[c] + sh1s[c], 0.f);
                    unsigned short h = f2bf(v);
                    vh[e] = (short)h;
                    vl[e] = (short)f2bf(v - bf2f(h));
                }
                *(short8*)&aH[n * H1S + cb + e8 * 8] = vh;
                *(short8*)&aL[n * H1S + cb + e8 * 8] = vl;
            }
        }
        __syncthreads();

        // ---- conv2: wave 4mt x 4nt ----
        {
            float4v acc[4][4];
            #pragma unroll
            for (int i = 0; i < 4; ++i)
                #pragma unroll
                for (int j = 0; j < 4; ++j) acc[i][j] = zero4;
            for (int ks = 0; ks < 4; ++ks) {
                int ko = ks * 32 + lq * 8;
                short8 bh[4], bl[4];
                #pragma unroll
                for (int j = 0; j < 4; ++j) {
                    bh[j] = *(const short8*)&aH[(j * 16 + lrow) * H1S + ko];
                    bl[j] = *(const short8*)&aL[(j * 16 + lrow) * H1S + ko];
                }
                #pragma unroll
                for (int i = 0; i < 4; ++i) {
                    int m = (wave * 4 + i) * 16 + lrow;
                    short8 ah = *(const short8*)&w2hg[m * C1 + ko];
                    short8 al = *(const short8*)&w2lg[m * C1 + ko];
                    #pragma unroll
                    for (int j = 0; j < 4; ++j) {
                        acc[i][j] = MFMA16(ah, bh[j], acc[i][j]);
                        acc[i][j] = MFMA16(ah, bl[j], acc[i][j]);
                        acc[i][j] = MFMA16(al, bh[j], acc[i][j]);
                    }
                }
            }
            #pragma unroll
            for (int i = 0; i < 4; ++i) {
                int mb = (wave * 4 + i) * 16 + lq * 4;
                float bb0 = b2s[mb], bb1 = b2s[mb+1], bb2 = b2s[mb+2], bb3 = b2s[mb+3];
                #pragma unroll
                for (int j = 0; j < 4; ++j) {
                    int n = j * 16 + lrow;
                    short4v p;
                    p[0] = (short)f2bf(acc[i][j][0] + bb0);
                    p[1] = (short)f2bf(acc[i][j][1] + bb1);
                    p[2] = (short)f2bf(acc[i][j][2] + bb2);
                    p[3] = (short)f2bf(acc[i][j][3] + bb3);
                    *(short4v*)&f2s[n * F2S + mb] = p;
                }
            }
        }
        __syncthreads();

        // ---- conv3 + conv4 fused over 4 k-slices (wave: 2mt x 4nt) ----
        float4v acc4[2][4];
        #pragma unroll
        for (int i = 0; i < 2; ++i)
            #pragma unroll
            for (int j = 0; j < 4; ++j) acc4[i][j] = zero4;

        for (int sl = 0; sl < 4; ++sl) {
            float4v acc3[2][4];
            #pragma unroll
            for (int i = 0; i < 2; ++i)
                #pragma unroll
                for (int j = 0; j < 4; ++j) acc3[i][j] = zero4;
            for (int ks = 0; ks < 8; ++ks) {
                int ko = ks * 32 + lq * 8;
                short8 bfr[4];
                #pragma unroll
                for (int j = 0; j < 4; ++j)
                    bfr[j] = *(const short8*)&f2s[(j * 16 + lrow) * F2S + ko];
                #pragma unroll
                for (int i = 0; i < 2; ++i) {
                    int mg = sl * 128 + (wave * 2 + i) * 16 + lrow;
                    short8 ah = *(const short8*)&w3bh[mg * C2 + ko];
                    short8 al = *(const short8*)&w3bl[mg * C2 + ko];
                    #pragma unroll
                    for (int j = 0; j < 4; ++j) {
                        acc3[i][j] = MFMA16(ah, bfr[j], acc3[i][j]);
                        acc3[i][j] = MFMA16(al, bfr[j], acc3[i][j]);
                    }
                }
            }
            __syncthreads();   // prior conv4 done reading ovl
            #pragma unroll
            for (int i = 0; i < 2; ++i) {
                int mbl = (wave * 2 + i) * 16 + lq * 4;
                int mg  = sl * 128 + mbl;
                float cA0 = c3s[mg],   sA0 = sc2s[mg],   hA0 = sh2s[mg];
                float cA1 = c3s[mg+1], sA1 = sc2s[mg+1], hA1 = sh2s[mg+1];
                float cA2 = c3s[mg+2], sA2 = sc2s[mg+2], hA2 = sh2s[mg+2];
                float cA3 = c3s[mg+3], sA3 = sc2s[mg+3], hA3 = sh2s[mg+3];
                #pragma unroll
                for (int j = 0; j < 4; ++j) {
                    int n = j * 16 + lrow;
                    float v0 = fmaxf((acc3[i][j][0] + cA0) * sA0 + hA0, 0.f);
                    float v1 = fmaxf((acc3[i][j][1] + cA1) * sA1 + hA1, 0.f);
                    float v2 = fmaxf((acc3[i][j][2] + cA2) * sA2 + hA2, 0.f);
                    float v3 = fmaxf((acc3[i][j][3] + cA3) * sA3 + hA3, 0.f);
                    short4v ph, pl;
                    unsigned short h0 = f2bf(v0), h1 = f2bf(v1), h2 = f2bf(v2), h3 = f2bf(v3);
                    ph[0]=(short)h0; ph[1]=(short)h1; ph[2]=(short)h2; ph[3]=(short)h3;
                    pl[0]=(short)f2bf(v0-bf2f(h0)); pl[1]=(short)f2bf(v1-bf2f(h1));
                    pl[2]=(short)f2bf(v2-bf2f(h2)); pl[3]=(short)f2bf(v3-bf2f(h3));
                    *(short4v*)&aH[n * H1S + mbl] = ph;
                    *(short4v*)&aL[n * H1S + mbl] = pl;
                }
            }
            __syncthreads();
            for (int ks = 0; ks < 4; ++ks) {
                int ko = ks * 32 + lq * 8;
                short8 bh[4], bl[4];
                #pragma unroll
                for (int j = 0; j < 4; ++j) {
                    bh[j] = *(const short8*)&aH[(j * 16 + lrow) * H1S + ko];
                    bl[j] = *(const short8*)&aL[(j * 16 + lrow) * H1S + ko];
                }
                #pragma unroll
                for (int i = 0; i < 2; ++i) {
                    int m = (wave * 2 + i) * 16 + lrow;
                    short8 ah = *(const short8*)&w4hg[m * C3 + sl * 128 + ko];
                    short8 al = *(const short8*)&w4lg[m * C3 + sl * 128 + ko];
                    #pragma unroll
                    for (int j = 0; j < 4; ++j) {
                        acc4[i][j] = MFMA16(ah, bh[j], acc4[i][j]);
                        acc4[i][j] = MFMA16(ah, bl[j], acc4[i][j]);
                        acc4[i][j] = MFMA16(al, bh[j], acc4[i][j]);
                    }
                }
            }
        }
        // fold chunk's conv4 into running max
        #pragma unroll
        for (int i = 0; i < 2; ++i)
            #pragma unroll
            for (int r = 0; r < 4; ++r) {
                float v = rm[i][r];
                #pragma unroll
                for (int j = 0; j < 4; ++j) v = fmaxf(v, acc4[i][j][r]);
                rm[i][r] = v;
            }
    }

    // ---- max over the 16 n-lanes ----
    #pragma unroll
    for (int i = 0; i < 2; ++i) {
        #pragma unroll
        for (int r = 0; r < 4; ++r) {
            float v = rm[i][r];
            v = fmaxf(v, __shfl_xor(v, 1));
            v = fmaxf(v, __shfl_xor(v, 2));
            v = fmaxf(v, __shfl_xor(v, 4));
            v = fmaxf(v, __shfl_xor(v, 8));
            if (lrow == 0) fmp[(wave * 2 + i) * 16 + lq * 4 + r] = v;
        }
    }
    __syncthreads();
    if (t < C4) {
        float v = fmp[t] + b4[t];
        int b = blk >> 11, n = blk & (NPTS - 1);
        out[((size_t)b * C4 + t) * NPTS + n] = v;
    }
}

// ---------------------------------------------------------------------------
extern "C" void kernel_launch(void* const* d_in, const int* in_sizes, int n_in,
                              void* d_out, int out_size, void* d_ws, size_t ws_size,
                              hipStream_t stream) {
    const float* pos = (const float*)d_in[0];
    const float* w1  = (const float*)d_in[1];
    const float* b1  = (const float*)d_in[2];
    const float* g1  = (const float*)d_in[3];
    const float* be1 = (const float*)d_in[4];
    const float* w2  = (const float*)d_in[5];
    const float* b2  = (const float*)d_in[6];
    const float* w3  = (const float*)d_in[7];
    const float* b3  = (const float*)d_in[8];
    const float* g2  = (const float*)d_in[9];
    const float* be2 = (const float*)d_in[10];
    const float* w4  = (const float*)d_in[11];
    const float* b4  = (const float*)d_in[12];
    float* out = (float*)d_out;
    float* ws  = (float*)d_ws;

    float* gp      = ws;                          // 1572864
    float* w3t     = gp + 1572864;                // 262144
    float* bn1sumr = w3t + 262144;                // 1024
    float* bn1sqr  = bn1sumr + NREP * C1;         // 1024
    float* bn2sumr = bn1sqr + NREP * C1;          // 4096
    float* bn2sqr  = bn2sumr + NREP * C3;         // 4096
    float* sc1     = bn2sqr + NREP * C3;          // 128
    float* sh1     = sc1 + 128;                   // 128
    float* sc2     = sh1 + 128;                   // 512
    float* sh2     = sc2 + 512;                   // 512
    float* c3buf   = sh2 + 512;                   // 4096*512 = 2097152
    unsigned short* uw = (unsigned short*)(c3buf + 2097152);
    unsigned short* w2hg = uw;                    // 32768
    unsigned short* w2lg = uw + 32768;            // 32768
    unsigned short* w3bh = uw + 65536;            // 131072
    unsigned short* w3bl = uw + 196608;           // 131072
    unsigned short* w4hg = uw + 327680;           // 65536
    unsigned short* w4lg = uw + 393216;           // 65536

    hipMemsetAsync(bn1sumr, 0, (size_t)(2 * NREP * C1 + 2 * NREP * C3) * sizeof(float), stream);
    prep_kernel<<<512, 256, 0, stream>>>(w2, w3, w4, w3t,
                                         w2hg, w2lg, w3bh, w3bl, w4hg, w4lg);
    knn_kernel<<<NGROUP, 256, 0, stream>>>(pos, w1, b1, out, gp, bn1sumr, bn1sqr);
    bn_finalize<<<1, 128, 0, stream>>>(bn1sumr, bn1sqr, g1, be1, sc1, sh1, C1, 1.f / 524288.f);
    stats2_mfma_kernel<<<NGROUP, 256, 0, stream>>>(gp, w1, b1, sc1, sh1,
                                                   w2hg, w2lg, b2, w3t, w3bh, w3bl, b3,
                                                   c3buf, bn2sumr, bn2sqr);
    bn_finalize<<<1, 512, 0, stream>>>(bn2sumr, bn2sqr, g2, be2, sc2, sh2, C3, 1.f / 524288.f);
    final_mfma_kernel<<<NGROUP, 256, 0, stream>>>(gp, w1, b1, sc1, sh1,
                                                  w2hg, w2lg, b2, w3bh, w3bl,
                                                  sc2, sh2, w4hg, w4lg, b4, c3buf, out);
}

// Round 10
// 1632.161 us; speedup vs baseline: 1.3894x; 1.3894x over previous
//
#include <hip/hip_runtime.h>
#include <stdint.h>

#define NPTS  2048
#define BATCH 2
#define KNN   128
#define C1    128
#define C2    256
#define C3    512
#define C4    128
#define NGROUP (BATCH * NPTS)    // 4096
#define FEAT_ELEMS (BATCH * C4 * NPTS)  // 524288
#define HBINS 2048
#define NREP  8

typedef short short8 __attribute__((ext_vector_type(8)));
typedef short short4v __attribute__((ext_vector_type(4)));
typedef float float4v __attribute__((ext_vector_type(4)));
#define MFMA16(a, b, c) __builtin_amdgcn_mfma_f32_16x16x32_bf16(a, b, c, 0, 0, 0)

__device__ __host__ inline unsigned short f2bf(float x) {
    unsigned u = __float_as_uint(x);
    return (unsigned short)((u + 0x7fffu + ((u >> 16) & 1u)) >> 16);
}
__device__ inline float bf2f(unsigned short s) {
    return __uint_as_float(((unsigned)s) << 16);
}

// ---------------------------------------------------------------------------
__global__ void prep_kernel(const float* __restrict__ w2, const float* __restrict__ w3,
                            const float* __restrict__ w4,
                            float* __restrict__ w3t,
                            unsigned short* __restrict__ w2hg, unsigned short* __restrict__ w2lg,
                            unsigned short* __restrict__ w3bh, unsigned short* __restrict__ w3bl,
                            unsigned short* __restrict__ w4hg, unsigned short* __restrict__ w4lg) {
    int tid = blockIdx.x * blockDim.x + threadIdx.x;
    int stride = gridDim.x * blockDim.x;
    for (int i = tid; i < C2 * C1; i += stride) {
        float v = w2[i];
        unsigned short h = f2bf(v);
        w2hg[i] = h; w2lg[i] = f2bf(v - bf2f(h));
    }
    for (int i = tid; i < C3 * C3; i += stride) w3t[(i & (C3 - 1)) * C3 + (i >> 9)] = w3[i];
    for (int i = tid; i < C3 * C2; i += stride) {
        int m = i >> 8, k = i & 255;
        float v = w3[m * C3 + C2 + k];
        unsigned short h = f2bf(v);
        w3bh[i] = h; w3bl[i] = f2bf(v - bf2f(h));
    }
    for (int i = tid; i < C4 * C3; i += stride) {
        float v = w4[i];
        unsigned short h = f2bf(v);
        w4hg[i] = h; w4lg[i] = f2bf(v - bf2f(h));
    }
}

// ---------------------------------------------------------------------------
// K0: exact kNN via 2-level radix select. Low-barrier version: wave-level
// shfl prefix scans (2 barriers each) and barrier-free rank-by-count
// selection instead of the 36-barrier bitonic. Distance math bit-identical
// to the reference (sq no-fma; dot k-ascending fma chain; sqrtf).
__launch_bounds__(256)
__global__ void knn_kernel(const float* __restrict__ pos,
                           const float* __restrict__ w1, const float* __restrict__ b1,
                           float* __restrict__ out,
                           float* __restrict__ gp,
                           float* __restrict__ bn1sumr, float* __restrict__ bn1sqr) {
    __shared__ float px[NPTS], py[NPTS], pz[NPTS];
    __shared__ unsigned int dbits[NPTS];
    __shared__ unsigned int hist[HBINS];
    __shared__ unsigned int wsum[4];
    __shared__ unsigned long long cand[256];
    __shared__ float gsx[KNN], gsy[KNN], gsz[KNN];
    __shared__ float red[256];
    __shared__ unsigned int s_b1, s_c0, s_p22, s_cnt;

    int t = threadIdx.x;
    int lane = t & 63, wave = t >> 6;
    int blk = blockIdx.x;
    int b = blk >> 11, n = blk & (NPTS - 1);
    const float* pb = pos + (size_t)b * NPTS * 3;
    for (int i = t; i < NPTS; i += 256) {
        px[i] = pb[i * 3 + 0]; py[i] = pb[i * 3 + 1]; pz[i] = pb[i * 3 + 2];
    }
    for (int i = t; i < HBINS; i += 256) hist[i] = 0;
    if (t == 0) s_cnt = 0;
    __syncthreads();

    float qx = px[n], qy = py[n], qz = pz[n];
    {
        #pragma clang fp contract(off)
        float sqi = (qx * qx + qy * qy) + qz * qz;
        for (int j = t; j < NPTS; j += 256) {
            float xj = px[j], yj = py[j], zj = pz[j];
            float sqj = (xj * xj + yj * yj) + zj * zj;
            float dot = fmaf(qz, zj, fmaf(qy, yj, qx * xj));
            float d2 = (sqi + sqj) - 2.0f * dot;
            float dist = sqrtf(fmaxf(d2, 0.0f));
            unsigned int bits = __float_as_uint(dist);
            dbits[j] = bits;
            atomicAdd(&hist[bits >> 20], 1u);
        }
    }
    __syncthreads();

    // ---- pass 1: find bin B1 containing rank 127 (wave-shfl scan) ----
    {
        unsigned int s0 = 0;
        #pragma unroll
        for (int q = 0; q < 8; ++q) s0 += hist[t * 8 + q];
        unsigned int s = s0;
        #pragma unroll
        for (int off = 1; off < 64; off <<= 1) {
            unsigned int u = __shfl_up(s, off);
            if (lane >= off) s += u;
        }
        if (lane == 63) wsum[wave] = s;
        __syncthreads();
        unsigned int woff = 0;
        for (int w = 0; w < 4; ++w) woff += (w < wave) ? wsum[w] : 0u;
        unsigned int incl = s + woff;
        unsigned int before = incl - s0;
        if (before <= 127u && 127u < incl) {
            unsigned int c = before;
            for (int q = 0; q < 8; ++q) {
                unsigned int h = hist[t * 8 + q];
                if (c + h > 127u) { s_b1 = t * 8 + q; s_c0 = c; break; }
                c += h;
            }
        }
    }
    __syncthreads();
    unsigned int B1 = s_b1, c0 = s_c0;
    // ---- pass 2: refine within B1 on bits[19:9] ----
    for (int i = t; i < HBINS; i += 256) hist[i] = 0;
    __syncthreads();
    for (int j = t; j < NPTS; j += 256) {
        unsigned int bits = dbits[j];
        if ((bits >> 20) == B1) atomicAdd(&hist[(bits >> 9) & 0x7FFu], 1u);
    }
    __syncthreads();
    {
        unsigned int target = 127u - c0;
        unsigned int s0 = 0;
        #pragma unroll
        for (int q = 0; q < 8; ++q) s0 += hist[t * 8 + q];
        unsigned int s = s0;
        #pragma unroll
        for (int off = 1; off < 64; off <<= 1) {
            unsigned int u = __shfl_up(s, off);
            if (lane >= off) s += u;
        }
        if (lane == 63) wsum[wave] = s;
        __syncthreads();
        unsigned int woff = 0;
        for (int w = 0; w < 4; ++w) woff += (w < wave) ? wsum[w] : 0u;
        unsigned int incl = s + woff;
        unsigned int before = incl - s0;
        if (before <= target && target < incl) {
            unsigned int c = before;
            for (int q = 0; q < 8; ++q) {
                unsigned int h = hist[t * 8 + q];
                if (c + h > target) { s_p22 = (B1 << 11) | (unsigned)(t * 8 + q); break; }
                c += h;
            }
        }
    }
    cand[t] = 0xFFFFFFFFFFFFFFFFull;
    __syncthreads();
    unsigned int P22 = s_p22;
    // ---- collect candidates: prefix22 <= P22 (top-128 provably contained) ----
    for (int j = t; j < NPTS; j += 256) {
        unsigned int bits = dbits[j];
        if ((bits >> 9) <= P22) {
            unsigned int pos_ = atomicAdd(&s_cnt, 1u);
            if (pos_ < 256u) cand[pos_] = ((unsigned long long)bits << 32) | (unsigned int)j;
        }
    }
    __syncthreads();
    // ---- rank-by-count selection (keys unique; rank = #smaller keys) ----
    {
        unsigned long long myk = cand[t];
        int rank = 0;
        #pragma unroll 8
        for (int j = 0; j < 256; ++j) rank += (cand[j] < myk) ? 1 : 0;
        if (myk != 0xFFFFFFFFFFFFFFFFull && rank < KNN) {
            unsigned int j = (unsigned int)(myk & 0xffffffffu);
            out[FEAT_ELEMS + (size_t)blk * KNN + rank] = (float)j;
            float gx_ = px[j] - qx, gy_ = py[j] - qy, gz_ = pz[j] - qz;
            gsx[rank] = gx_; gsy[rank] = gy_; gsz[rank] = gz_;
            float* g = gp + ((size_t)blk * KNN + rank) * 3;
            g[0] = gx_; g[1] = gy_; g[2] = gz_;
        }
    }
    __syncthreads();
    // ---- BN1 moments ----
    int c = t & (C1 - 1);
    int half = t >> 7;
    float wa = w1[c * 3 + 0], wb = w1[c * 3 + 1], wc = w1[c * 3 + 2], bc = b1[c];
    float s = 0.f, q = 0.f;
    for (int r = half * 64; r < half * 64 + 64; ++r) {
        float f = wa * gsx[r] + wb * gsy[r] + wc * gsz[r] + bc;
        s += f; q += f * f;
    }
    red[t] = s; __syncthreads();
    int rep = blk & (NREP - 1);
    if (t < C1) atomicAdd(bn1sumr + rep * C1 + t, red[t] + red[t + C1]);
    __syncthreads();
    red[t] = q; __syncthreads();
    if (t < C1) atomicAdd(bn1sqr + rep * C1 + t, red[t] + red[t + C1]);
}

// ---------------------------------------------------------------------------
__global__ void bn_finalize(const float* __restrict__ sumr, const float* __restrict__ sqr,
                            const float* __restrict__ g, const float* __restrict__ be,
                            float* __restrict__ scale, float* __restrict__ shift,
                            int nch, float inv_count) {
    int c = blockIdx.x * blockDim.x + threadIdx.x;
    if (c < nch) {
        float s = 0.f, q = 0.f;
        for (int r = 0; r < NREP; ++r) { s += sumr[r * nch + c]; q += sqr[r * nch + c]; }
        float m = s * inv_count;
        float v = fmaxf(q * inv_count - m * m, 0.f);
        float sc = g[c] / sqrtf(v + 1e-5f);
        scale[c] = sc;
        shift[c] = be[c] - m * sc;
    }
}

#define H1S 136   // h1/g3 row stride (shorts)
#define F2S 264   // f2 row stride (shorts)

// ---------------------------------------------------------------------------
// stats2 (r6 shape: 16x16 MFMA, 256 thr, N=128, (256,1) — the proven optimum;
// r7-r9 occupancy experiments all regressed: smaller tiles expose MFMA
// latency, (256,2) spills ~100KB/block to scratch).
__launch_bounds__(256, 1)
__global__ void stats2_mfma_kernel(const float* __restrict__ gp,
                                   const float* __restrict__ w1, const float* __restrict__ b1,
                                   const float* __restrict__ sc1, const float* __restrict__ sh1,
                                   const unsigned short* __restrict__ w2hg, const unsigned short* __restrict__ w2lg,
                                   const float* __restrict__ b2,
                                   const float* __restrict__ w3t,
                                   const unsigned short* __restrict__ w3bh, const unsigned short* __restrict__ w3bl,
                                   const float* __restrict__ b3,
                                   float* __restrict__ c3buf,
                                   float* __restrict__ bn2sumr, float* __restrict__ bn2sqr) {
    __shared__ __align__(16) unsigned short ovl[2 * 128 * H1S];   // h1 hi/lo
    __shared__ __align__(16) unsigned short f2s[128 * F2S];       // f2 single bf16 [n][c2]
    __shared__ float gfl[KNN * 3];
    __shared__ float w1s[C1 * 3], b1s[C1], sc1s[C1], sh1s[C1], b2s[C2];
    __shared__ float fgs[C2];
    __shared__ float c3s[C3];

    unsigned short* aH = ovl;
    unsigned short* aL = ovl + 128 * H1S;

    int t = threadIdx.x, blk = blockIdx.x;
    int lane = t & 63, wave = t >> 6;
    int lrow = lane & 15, lq = lane >> 4;

    const float* g = gp + (size_t)blk * KNN * 3;
    for (int i = t; i < KNN * 3; i += 256) gfl[i] = g[i];
    for (int i = t; i < C1 * 3; i += 256) w1s[i] = w1[i];
    if (t < C1) { b1s[t] = b1[t]; sc1s[t] = sc1[t]; sh1s[t] = sh1[t]; }
    b2s[t] = b2[t];
    __syncthreads();

    // ---- conv1 + BN1 + ReLU -> h1 hi/lo ----
    {
        int n = t >> 1;
        int cb = (t & 1) * 64;
        float gx = gfl[n * 3], gy = gfl[n * 3 + 1], gz = gfl[n * 3 + 2];
        #pragma unroll
        for (int e8 = 0; e8 < 8; ++e8) {
            short8 vh, vl;
            #pragma unroll
            for (int e = 0; e < 8; ++e) {
                int c = cb + e8 * 8 + e;
                float f = w1s[c*3] * gx + w1s[c*3+1] * gy + w1s[c*3+2] * gz + b1s[c];
                float v = fmaxf(f * sc1s[c] + sh1s[c], 0.f);
                unsigned short h = f2bf(v);
                vh[e] = (short)h;
                vl[e] = (short)f2bf(v - bf2f(h));
            }
            *(short8*)&aH[n * H1S + cb + e8 * 8] = vh;
            *(short8*)&aL[n * H1S + cb + e8 * 8] = vl;
        }
    }
    __syncthreads();

    const float4v zero4 = {0.f, 0.f, 0.f, 0.f};

    // ---- conv2 MFMA: M=256, K=128, N=128 ----
    {
        float4v acc2[4][8];
        #pragma unroll
        for (int i = 0; i < 4; ++i)
            #pragma unroll
            for (int j = 0; j < 8; ++j) acc2[i][j] = zero4;
        for (int ks = 0; ks < 4; ++ks) {
            int ko = ks * 32 + lq * 8;
            short8 bh[8], bl[8];
            #pragma unroll
            for (int j = 0; j < 8; ++j) {
                bh[j] = *(const short8*)&aH[(j * 16 + lrow) * H1S + ko];
                bl[j] = *(const short8*)&aL[(j * 16 + lrow) * H1S + ko];
            }
            #pragma unroll
            for (int i = 0; i < 4; ++i) {
                int m = (wave * 4 + i) * 16 + lrow;
                short8 ah = *(const short8*)&w2hg[m * C1 + ko];
                short8 al = *(const short8*)&w2lg[m * C1 + ko];
                #pragma unroll
                for (int j = 0; j < 8; ++j) {
                    acc2[i][j] = MFMA16(ah, bh[j], acc2[i][j]);
                    acc2[i][j] = MFMA16(ah, bl[j], acc2[i][j]);
                    acc2[i][j] = MFMA16(al, bh[j], acc2[i][j]);
                }
            }
        }
        // epilogue: bias, fg (max over n), pack f2 single bf16
        #pragma unroll
        for (int i = 0; i < 4; ++i) {
            int mb = (wave * 4 + i) * 16 + lq * 4;
            float bb0 = b2s[mb], bb1 = b2s[mb+1], bb2 = b2s[mb+2], bb3 = b2s[mb+3];
            float mx0 = -3.4e38f, mx1 = -3.4e38f, mx2 = -3.4e38f, mx3 = -3.4e38f;
            #pragma unroll
            for (int j = 0; j < 8; ++j) {
                int n = j * 16 + lrow;
                float v0 = acc2[i][j][0] + bb0, v1 = acc2[i][j][1] + bb1;
                float v2 = acc2[i][j][2] + bb2, v3 = acc2[i][j][3] + bb3;
                short4v p;
                p[0] = (short)f2bf(v0); p[1] = (short)f2bf(v1);
                p[2] = (short)f2bf(v2); p[3] = (short)f2bf(v3);
                *(short4v*)&f2s[n * F2S + mb] = p;
                mx0 = fmaxf(mx0, v0); mx1 = fmaxf(mx1, v1);
                mx2 = fmaxf(mx2, v2); mx3 = fmaxf(mx3, v3);
            }
            float mx[4] = {mx0, mx1, mx2, mx3};
            #pragma unroll
            for (int r = 0; r < 4; ++r) {
                float v = mx[r];
                v = fmaxf(v, __shfl_xor(v, 1));
                v = fmaxf(v, __shfl_xor(v, 2));
                v = fmaxf(v, __shfl_xor(v, 4));
                v = fmaxf(v, __shfl_xor(v, 8));
                if (lrow == 0) fgs[mb + r] = v;
            }
        }
    }
    __syncthreads();

    // ---- c3 = b3 + W3a·fg (fp32) ----
    {
        float c3a = b3[t], c3b = b3[t + 256];
        for (int c2_ = 0; c2_ < C2; ++c2_) {
            float f = fgs[c2_];
            c3a += w3t[(size_t)c2_ * C3 + t] * f;
            c3b += w3t[(size_t)c2_ * C3 + t + 256] * f;
        }
        c3s[t] = c3a; c3s[t + 256] = c3b;
        c3buf[(size_t)blk * C3 + t] = c3a;
        c3buf[(size_t)blk * C3 + t + 256] = c3b;
    }
    __syncthreads();

    // ---- conv3 in 4 m-slices + BN2 moments ----
    int rep = blk & (NREP - 1);
    for (int s = 0; s < 4; ++s) {
        float4v acc3[2][8];
        #pragma unroll
        for (int i = 0; i < 2; ++i)
            #pragma unroll
            for (int j = 0; j < 8; ++j) acc3[i][j] = zero4;
        for (int ks = 0; ks < 8; ++ks) {
            int ko = ks * 32 + lq * 8;
            short8 bh[8];
            #pragma unroll
            for (int j = 0; j < 8; ++j)
                bh[j] = *(const short8*)&f2s[(j * 16 + lrow) * F2S + ko];
            #pragma unroll
            for (int i = 0; i < 2; ++i) {
                int mg = s * 128 + (wave * 2 + i) * 16 + lrow;
                short8 ah = *(const short8*)&w3bh[mg * C2 + ko];
                short8 al = *(const short8*)&w3bl[mg * C2 + ko];
                #pragma unroll
                for (int j = 0; j < 8; ++j) {
                    acc3[i][j] = MFMA16(ah, bh[j], acc3[i][j]);
                    acc3[i][j] = MFMA16(al, bh[j], acc3[i][j]);
                }
            }
        }
        #pragma unroll
        for (int i = 0; i < 2; ++i) {
            #pragma unroll
            for (int r = 0; r < 4; ++r) {
                float sS = 0.f, qS = 0.f;
                #pragma unroll
                for (int j = 0; j < 8; ++j) {
                    float v = acc3[i][j][r];
                    sS += v; qS += v * v;
                }
                sS += __shfl_xor(sS, 1); qS += __shfl_xor(qS, 1);
                sS += __shfl_xor(sS, 2); qS += __shfl_xor(qS, 2);
                sS += __shfl_xor(sS, 4); qS += __shfl_xor(qS, 4);
                sS += __shfl_xor(sS, 8); qS += __shfl_xor(qS, 8);
                if (lrow == 0) {
                    int mg = s * 128 + (wave * 2 + i) * 16 + lq * 4 + r;
                    float cc = c3s[mg];
                    atomicAdd(bn2sumr + rep * C3 + mg, sS + 128.f * cc);
                    atomicAdd(bn2sqr  + rep * C3 + mg, qS + 2.f * cc * sS + 128.f * cc * cc);
                }
            }
        }
    }
}

// ---------------------------------------------------------------------------
// final (r6 shape: 16x16 MFMA, 256 thr, N=128, (256,1)).
__launch_bounds__(256, 1)
__global__ void final_mfma_kernel(const float* __restrict__ gp,
                                  const float* __restrict__ w1, const float* __restrict__ b1,
                                  const float* __restrict__ sc1, const float* __restrict__ sh1,
                                  const unsigned short* __restrict__ w2hg, const unsigned short* __restrict__ w2lg,
                                  const float* __restrict__ b2,
                                  const unsigned short* __restrict__ w3bh, const unsigned short* __restrict__ w3bl,
                                  const float* __restrict__ sc2, const float* __restrict__ sh2,
                                  const unsigned short* __restrict__ w4hg, const unsigned short* __restrict__ w4lg,
                                  const float* __restrict__ b4,
                                  const float* __restrict__ c3buf, float* __restrict__ out) {
    __shared__ __align__(16) unsigned short ovl[2 * 128 * H1S];
    __shared__ __align__(16) unsigned short f2s[128 * F2S];
    __shared__ float gfl[KNN * 3];
    __shared__ float w1s[C1 * 3], b1s[C1], sc1s[C1], sh1s[C1], b2s[C2];
    __shared__ float c3s[C3], sc2s[C3], sh2s[C3];
    __shared__ float fmaxbuf[C4];

    unsigned short* aH = ovl;
    unsigned short* aL = ovl + 128 * H1S;

    int t = threadIdx.x, blk = blockIdx.x;
    int lane = t & 63, wave = t >> 6;
    int lrow = lane & 15, lq = lane >> 4;

    const float* g = gp + (size_t)blk * KNN * 3;
    for (int i = t; i < KNN * 3; i += 256) gfl[i] = g[i];
    for (int i = t; i < C1 * 3; i += 256) w1s[i] = w1[i];
    if (t < C1) { b1s[t] = b1[t]; sc1s[t] = sc1[t]; sh1s[t] = sh1[t]; }
    b2s[t] = b2[t];
    for (int i = t; i < C3; i += 256) {
        c3s[i] = c3buf[(size_t)blk * C3 + i];
        sc2s[i] = sc2[i]; sh2s[i] = sh2[i];
    }
    __syncthreads();

    {
        int n = t >> 1;
        int cb = (t & 1) * 64;
        float gx = gfl[n * 3], gy = gfl[n * 3 + 1], gz = gfl[n * 3 + 2];
        #pragma unroll
        for (int e8 = 0; e8 < 8; ++e8) {
            short8 vh, vl;
            #pragma unroll
            for (int e = 0; e < 8; ++e) {
                int c = cb + e8 * 8 + e;
                float f = w1s[c*3] * gx + w1s[c*3+1] * gy + w1s[c*3+2] * gz + b1s[c];
                float v = fmaxf(f * sc1s[c] + sh1s[c], 0.f);
                unsigned short h = f2bf(v);
                vh[e] = (short)h;
                vl[e] = (short)f2bf(v - bf2f(h));
            }
            *(short8*)&aH[n * H1S + cb + e8 * 8] = vh;
            *(short8*)&aL[n * H1S + cb + e8 * 8] = vl;
        }
    }
    __syncthreads();

    const float4v zero4 = {0.f, 0.f, 0.f, 0.f};

    {
        float4v acc2[4][8];
        #pragma unroll
        for (int i = 0; i < 4; ++i)
            #pragma unroll
            for (int j = 0; j < 8; ++j) acc2[i][j] = zero4;
        for (int ks = 0; ks < 4; ++ks) {
            int ko = ks * 32 + lq * 8;
            short8 bh[8], bl[8];
            #pragma unroll
            for (int j = 0; j < 8; ++j) {
                bh[j] = *(const short8*)&aH[(j * 16 + lrow) * H1S + ko];
                bl[j] = *(const short8*)&aL[(j * 16 + lrow) * H1S + ko];
            }
            #pragma unroll
            for (int i = 0; i < 4; ++i) {
                int m = (wave * 4 + i) * 16 + lrow;
                short8 ah = *(const short8*)&w2hg[m * C1 + ko];
                short8 al = *(const short8*)&w2lg[m * C1 + ko];
                #pragma unroll
                for (int j = 0; j < 8; ++j) {
                    acc2[i][j] = MFMA16(ah, bh[j], acc2[i][j]);
                    acc2[i][j] = MFMA16(ah, bl[j], acc2[i][j]);
                    acc2[i][j] = MFMA16(al, bh[j], acc2[i][j]);
                }
            }
        }
        __syncthreads();
        #pragma unroll
        for (int i = 0; i < 4; ++i) {
            int mb = (wave * 4 + i) * 16 + lq * 4;
            float bb0 = b2s[mb], bb1 = b2s[mb+1], bb2 = b2s[mb+2], bb3 = b2s[mb+3];
            #pragma unroll
            for (int j = 0; j < 8; ++j) {
                int n = j * 16 + lrow;
                short4v p;
                p[0] = (short)f2bf(acc2[i][j][0] + bb0);
                p[1] = (short)f2bf(acc2[i][j][1] + bb1);
                p[2] = (short)f2bf(acc2[i][j][2] + bb2);
                p[3] = (short)f2bf(acc2[i][j][3] + bb3);
                *(short4v*)&f2s[n * F2S + mb] = p;
            }
        }
    }
    __syncthreads();

    float4v acc4[2][8];
    #pragma unroll
    for (int i = 0; i < 2; ++i)
        #pragma unroll
        for (int j = 0; j < 8; ++j) acc4[i][j] = zero4;

    for (int s = 0; s < 4; ++s) {
        float4v acc3[2][8];
        #pragma unroll
        for (int i = 0; i < 2; ++i)
            #pragma unroll
            for (int j = 0; j < 8; ++j) acc3[i][j] = zero4;
        for (int ks = 0; ks < 8; ++ks) {
            int ko = ks * 32 + lq * 8;
            short8 bh[8];
            #pragma unroll
            for (int j = 0; j < 8; ++j)
                bh[j] = *(const short8*)&f2s[(j * 16 + lrow) * F2S + ko];
            #pragma unroll
            for (int i = 0; i < 2; ++i) {
                int mg = s * 128 + (wave * 2 + i) * 16 + lrow;
                short8 ah = *(const short8*)&w3bh[mg * C2 + ko];
                short8 al = *(const short8*)&w3bl[mg * C2 + ko];
                #pragma unroll
                for (int j = 0; j < 8; ++j) {
                    acc3[i][j] = MFMA16(ah, bh[j], acc3[i][j]);
                    acc3[i][j] = MFMA16(al, bh[j], acc3[i][j]);
                }
            }
        }
        __syncthreads();
        #pragma unroll
        for (int i = 0; i < 2; ++i) {
            int mbl = (wave * 2 + i) * 16 + lq * 4;
            int mg  = s * 128 + mbl;
            float cA0 = c3s[mg],   sA0 = sc2s[mg],   hA0 = sh2s[mg];
            float cA1 = c3s[mg+1], sA1 = sc2s[mg+1], hA1 = sh2s[mg+1];
            float cA2 = c3s[mg+2], sA2 = sc2s[mg+2], hA2 = sh2s[mg+2];
            float cA3 = c3s[mg+3], sA3 = sc2s[mg+3], hA3 = sh2s[mg+3];
            #pragma unroll
            for (int j = 0; j < 8; ++j) {
                int n = j * 16 + lrow;
                float v0 = fmaxf((acc3[i][j][0] + cA0) * sA0 + hA0, 0.f);
                float v1 = fmaxf((acc3[i][j][1] + cA1) * sA1 + hA1, 0.f);
                float v2 = fmaxf((acc3[i][j][2] + cA2) * sA2 + hA2, 0.f);
                float v3 = fmaxf((acc3[i][j][3] + cA3) * sA3 + hA3, 0.f);
                short4v ph, pl;
                unsigned short h0 = f2bf(v0), h1 = f2bf(v1), h2 = f2bf(v2), h3 = f2bf(v3);
                ph[0]=(short)h0; ph[1]=(short)h1; ph[2]=(short)h2; ph[3]=(short)h3;
                pl[0]=(short)f2bf(v0-bf2f(h0)); pl[1]=(short)f2bf(v1-bf2f(h1));
                pl[2]=(short)f2bf(v2-bf2f(h2)); pl[3]=(short)f2bf(v3-bf2f(h3));
                *(short4v*)&aH[n * H1S + mbl] = ph;
                *(short4v*)&aL[n * H1S + mbl] = pl;
            }
        }
        __syncthreads();
        for (int ks = 0; ks < 4; ++ks) {
            int ko = ks * 32 + lq * 8;
            short8 bh[8], bl[8];
            #pragma unroll
            for (int j = 0; j < 8; ++j) {
                bh[j] = *(const short8*)&aH[(j * 16 + lrow) * H1S + ko];
                bl[j] = *(const short8*)&aL[(j * 16 + lrow) * H1S + ko];
            }
            #pragma unroll
            for (int i = 0; i < 2; ++i) {
                int m = (wave * 2 + i) * 16 + lrow;
                short8 ah = *(const short8*)&w4hg[m * C3 + s * 128 + ko];
                short8 al = *(const short8*)&w4lg[m * C3 + s * 128 + ko];
                #pragma unroll
                for (int j = 0; j < 8; ++j) {
                    acc4[i][j] = MFMA16(ah, bh[j], acc4[i][j]);
                    acc4[i][j] = MFMA16(ah, bl[j], acc4[i][j]);
                    acc4[i][j] = MFMA16(al, bh[j], acc4[i][j]);
                }
            }
        }
    }

    #pragma unroll
    for (int i = 0; i < 2; ++i) {
        #pragma unroll
        for (int r = 0; r < 4; ++r) {
            float v = -3.4e38f;
            #pragma unroll
            for (int j = 0; j < 8; ++j) v = fmaxf(v, acc4[i][j][r]);
            v = fmaxf(v, __shfl_xor(v, 1));
            v = fmaxf(v, __shfl_xor(v, 2));
            v = fmaxf(v, __shfl_xor(v, 4));
            v = fmaxf(v, __shfl_xor(v, 8));
            if (lrow == 0) fmaxbuf[(wave * 2 + i) * 16 + lq * 4 + r] = v;
        }
    }
    __syncthreads();
    if (t < C4) {
        float v = fmaxbuf[t] + b4[t];
        int b = blk >> 11, n = blk & (NPTS - 1);
        out[((size_t)b * C4 + t) * NPTS + n] = v;
    }
}

// ---------------------------------------------------------------------------
extern "C" void kernel_launch(void* const* d_in, const int* in_sizes, int n_in,
                              void* d_out, int out_size, void* d_ws, size_t ws_size,
                              hipStream_t stream) {
    const float* pos = (const float*)d_in[0];
    const float* w1  = (const float*)d_in[1];
    const float* b1  = (const float*)d_in[2];
    const float* g1  = (const float*)d_in[3];
    const float* be1 = (const float*)d_in[4];
    const float* w2  = (const float*)d_in[5];
    const float* b2  = (const float*)d_in[6];
    const float* w3  = (const float*)d_in[7];
    const float* b3  = (const float*)d_in[8];
    const float* g2  = (const float*)d_in[9];
    const float* be2 = (const float*)d_in[10];
    const float* w4  = (const float*)d_in[11];
    const float* b4  = (const float*)d_in[12];
    float* out = (float*)d_out;
    float* ws  = (float*)d_ws;

    float* gp      = ws;                          // 1572864
    float* w3t     = gp + 1572864;                // 262144
    float* bn1sumr = w3t + 262144;                // 1024
    float* bn1sqr  = bn1sumr + NREP * C1;         // 1024
    float* bn2sumr = bn1sqr + NREP * C1;          // 4096
    float* bn2sqr  = bn2sumr + NREP * C3;         // 4096
    float* sc1     = bn2sqr + NREP * C3;          // 128
    float* sh1     = sc1 + 128;                   // 128
    float* sc2     = sh1 + 128;                   // 512
    float* sh2     = sc2 + 512;                   // 512
    float* c3buf   = sh2 + 512;                   // 4096*512 = 2097152
    unsigned short* uw = (unsigned short*)(c3buf + 2097152);
    unsigned short* w2hg = uw;                    // 32768
    unsigned short* w2lg = uw + 32768;            // 32768
    unsigned short* w3bh = uw + 65536;            // 131072
    unsigned short* w3bl = uw + 196608;           // 131072
    unsigned short* w4hg = uw + 327680;           // 65536
    unsigned short* w4lg = uw + 393216;           // 65536

    hipMemsetAsync(bn1sumr, 0, (size_t)(2 * NREP * C1 + 2 * NREP * C3) * sizeof(float), stream);
    prep_kernel<<<512, 256, 0, stream>>>(w2, w3, w4, w3t,
                                         w2hg, w2lg, w3bh, w3bl, w4hg, w4lg);
    knn_kernel<<<NGROUP, 256, 0, stream>>>(pos, w1, b1, out, gp, bn1sumr, bn1sqr);
    bn_finalize<<<1, 128, 0, stream>>>(bn1sumr, bn1sqr, g1, be1, sc1, sh1, C1, 1.f / 524288.f);
    stats2_mfma_kernel<<<NGROUP, 256, 0, stream>>>(gp, w1, b1, sc1, sh1,
                                                   w2hg, w2lg, b2, w3t, w3bh, w3bl, b3,
                                                   c3buf, bn2sumr, bn2sqr);
    bn_finalize<<<1, 512, 0, stream>>>(bn2sumr, bn2sqr, g2, be2, sc2, sh2, C3, 1.f / 524288.f);
    final_mfma_kernel<<<NGROUP, 256, 0, stream>>>(gp, w1, b1, sc1, sh1,
                                                  w2hg, w2lg, b2, w3bh, w3bl,
                                                  sc2, sh2, w4hg, w4lg, b4, c3buf, out);
}